// Round 2
// baseline (2100.885 us; speedup 1.0000x reference)
//
#include <hip/hip_runtime.h>
#include <hip/hip_bf16.h>
#include <stdint.h>

#define HDIM 2048
#define BATCH 16
#define TLEN 512
#define TH   1048576        // TLEN*HDIM
#define OUT_MAIN 16777216   // BATCH*TLEN*HDIM

using floatx4 = __attribute__((ext_vector_type(4))) float;
using shortx8 = __attribute__((ext_vector_type(8))) short;
typedef unsigned long long ull;

// ---------------- cast kernels ----------------
__global__ void cast_x_kernel(const float* __restrict__ x, __hip_bfloat16* __restrict__ xb, int n) {
    int i = blockIdx.x * blockDim.x + threadIdx.x;
    int stride = gridDim.x * blockDim.x;
    for (; i < n; i += stride) xb[i] = __float2bfloat16(x[i]);
}

__global__ void cast_w_kernel(const float* __restrict__ W,
                              __hip_bfloat16* __restrict__ wxb,
                              __hip_bfloat16* __restrict__ whb) {
    int i = blockIdx.x * blockDim.x + threadIdx.x;
    int stride = gridDim.x * blockDim.x;
    for (; i < HDIM * HDIM; i += stride) {
        int g = i >> 11, k = i & (HDIM - 1);
        wxb[i] = __float2bfloat16(W[g * (2 * HDIM) + k]);
        whb[i] = __float2bfloat16(W[g * (2 * HDIM) + HDIM + k]);
    }
}

// Transpose + hi/lo split (after gemm_u; outputs alias dead xb).
__global__ void transpose_wh_kernel(const float* __restrict__ W,
                                    __hip_bfloat16* __restrict__ whT_hi,
                                    __hip_bfloat16* __restrict__ whT_lo,
                                    __hip_bfloat16* __restrict__ whb_lo) {
    __shared__ float tile[32][33];
    int bx = blockIdx.x * 32, by = blockIdx.y * 32;
    int tx = threadIdx.x, ty = threadIdx.y;  // (32,8)
#pragma unroll
    for (int r = 0; r < 32; r += 8) {
        float v = W[(size_t)(by + ty + r) * (2 * HDIM) + HDIM + bx + tx];
        tile[ty + r][tx] = v;
        __hip_bfloat16 h = __float2bfloat16(v);
        whb_lo[(size_t)(by + ty + r) * HDIM + bx + tx] = __float2bfloat16(v - __bfloat162float(h));
    }
    __syncthreads();
#pragma unroll
    for (int r = 0; r < 32; r += 8) {
        float v = tile[tx][ty + r];
        __hip_bfloat16 h = __float2bfloat16(v);
        whT_hi[(size_t)(bx + ty + r) * HDIM + by + tx] = h;
        whT_lo[(size_t)(bx + ty + r) * HDIM + by + tx] = __float2bfloat16(v - __bfloat162float(h));
    }
}

// ---------------- phase A: u = x @ Wx^T + b -> out (fp32) + ub (bf16) ----------------
__global__ __launch_bounds__(256) void gemm_u_kernel(
    const __hip_bfloat16* __restrict__ xb,
    const __hip_bfloat16* __restrict__ wxb,
    const float* __restrict__ bias,
    float* __restrict__ out,
    __hip_bfloat16* __restrict__ ub)
{
    __shared__ __align__(16) __hip_bfloat16 As[4 * 128 * 8];
    __shared__ __align__(16) __hip_bfloat16 Bs[4 * 128 * 8];

    const int j = threadIdx.x;
    const int m0 = blockIdx.x * 128;
    const int n0 = blockIdx.y * 128;
    const int w = j >> 6, lane = j & 63;
    const int wm = (w >> 1) * 64, wn = (w & 1) * 64;
    const int quad = lane >> 4, l15 = lane & 15;

    const int mA0 = j & 127, kg0 = j >> 7;
    const int mA1 = (j + 256) & 127, kg1 = (j + 256) >> 7;

    floatx4 acc[4][4] = {};

    shortx8 ra0 = *(const shortx8*)(xb  + (size_t)(m0 + mA0) * HDIM + kg0 * 8);
    shortx8 ra1 = *(const shortx8*)(xb  + (size_t)(m0 + mA1) * HDIM + kg1 * 8);
    shortx8 rb0 = *(const shortx8*)(wxb + (size_t)(n0 + mA0) * HDIM + kg0 * 8);
    shortx8 rb1 = *(const shortx8*)(wxb + (size_t)(n0 + mA1) * HDIM + kg1 * 8);

    for (int kt = 0; kt < 64; ++kt) {
        ((shortx8*)As)[kg0 * 128 + mA0] = ra0;
        ((shortx8*)As)[kg1 * 128 + mA1] = ra1;
        ((shortx8*)Bs)[kg0 * 128 + mA0] = rb0;
        ((shortx8*)Bs)[kg1 * 128 + mA1] = rb1;
        __syncthreads();

        if (kt < 63) {
            int k = (kt + 1) * 32;
            ra0 = *(const shortx8*)(xb  + (size_t)(m0 + mA0) * HDIM + k + kg0 * 8);
            ra1 = *(const shortx8*)(xb  + (size_t)(m0 + mA1) * HDIM + k + kg1 * 8);
            rb0 = *(const shortx8*)(wxb + (size_t)(n0 + mA0) * HDIM + k + kg0 * 8);
            rb1 = *(const shortx8*)(wxb + (size_t)(n0 + mA1) * HDIM + k + kg1 * 8);
        }

        shortx8 af[4], bf[4];
#pragma unroll
        for (int mt = 0; mt < 4; ++mt)
            af[mt] = ((const shortx8*)As)[quad * 128 + wm + mt * 16 + l15];
#pragma unroll
        for (int nt = 0; nt < 4; ++nt)
            bf[nt] = ((const shortx8*)Bs)[quad * 128 + wn + nt * 16 + l15];
#pragma unroll
        for (int mt = 0; mt < 4; ++mt)
#pragma unroll
            for (int nt = 0; nt < 4; ++nt)
                acc[mt][nt] = __builtin_amdgcn_mfma_f32_16x16x32_bf16(af[mt], bf[nt], acc[mt][nt], 0, 0, 0);
        __syncthreads();
    }

#pragma unroll
    for (int nt = 0; nt < 4; ++nt) {
        int gn = n0 + wn + nt * 16 + l15;
        float bv = bias[gn];
#pragma unroll
        for (int mt = 0; mt < 4; ++mt) {
#pragma unroll
            for (int r = 0; r < 4; ++r) {
                int gm = m0 + wm + mt * 16 + quad * 4 + r;
                float v = acc[mt][nt][r] + bv;
                out[(size_t)gm * HDIM + gn] = v;
                ub[(size_t)gm * HDIM + gn] = __float2bfloat16(v);
            }
        }
    }
}

// ---------------- Wh2 = Wh*Wh, hi/lo factors in, hi/lo out ----------------
__global__ __launch_bounds__(256) void gemm_w2_kernel(
    const __hip_bfloat16* __restrict__ whh,
    const __hip_bfloat16* __restrict__ whl,
    const __hip_bfloat16* __restrict__ wtH,
    const __hip_bfloat16* __restrict__ wtL,
    __hip_bfloat16* __restrict__ w2h,
    __hip_bfloat16* __restrict__ w2l)
{
    __shared__ __align__(16) __hip_bfloat16 AsH[4 * 128 * 8];
    __shared__ __align__(16) __hip_bfloat16 AsL[4 * 128 * 8];
    __shared__ __align__(16) __hip_bfloat16 BsH[4 * 128 * 8];
    __shared__ __align__(16) __hip_bfloat16 BsL[4 * 128 * 8];

    const int j = threadIdx.x;
    const int m0 = blockIdx.x * 128;
    const int n0 = blockIdx.y * 128;
    const int w = j >> 6, lane = j & 63;
    const int wm = (w >> 1) * 64, wn = (w & 1) * 64;
    const int quad = lane >> 4, l15 = lane & 15;

    const int mA0 = j & 127, kg0 = j >> 7;
    const int mA1 = (j + 256) & 127, kg1 = (j + 256) >> 7;

    floatx4 acc[4][4] = {};

    shortx8 rah0 = *(const shortx8*)(whh + (size_t)(m0 + mA0) * HDIM + kg0 * 8);
    shortx8 rah1 = *(const shortx8*)(whh + (size_t)(m0 + mA1) * HDIM + kg1 * 8);
    shortx8 ral0 = *(const shortx8*)(whl + (size_t)(m0 + mA0) * HDIM + kg0 * 8);
    shortx8 ral1 = *(const shortx8*)(whl + (size_t)(m0 + mA1) * HDIM + kg1 * 8);
    shortx8 rbh0 = *(const shortx8*)(wtH + (size_t)(n0 + mA0) * HDIM + kg0 * 8);
    shortx8 rbh1 = *(const shortx8*)(wtH + (size_t)(n0 + mA1) * HDIM + kg1 * 8);
    shortx8 rbl0 = *(const shortx8*)(wtL + (size_t)(n0 + mA0) * HDIM + kg0 * 8);
    shortx8 rbl1 = *(const shortx8*)(wtL + (size_t)(n0 + mA1) * HDIM + kg1 * 8);

    for (int kt = 0; kt < 64; ++kt) {
        ((shortx8*)AsH)[kg0 * 128 + mA0] = rah0;
        ((shortx8*)AsH)[kg1 * 128 + mA1] = rah1;
        ((shortx8*)AsL)[kg0 * 128 + mA0] = ral0;
        ((shortx8*)AsL)[kg1 * 128 + mA1] = ral1;
        ((shortx8*)BsH)[kg0 * 128 + mA0] = rbh0;
        ((shortx8*)BsH)[kg1 * 128 + mA1] = rbh1;
        ((shortx8*)BsL)[kg0 * 128 + mA0] = rbl0;
        ((shortx8*)BsL)[kg1 * 128 + mA1] = rbl1;
        __syncthreads();

        if (kt < 63) {
            int k = (kt + 1) * 32;
            rah0 = *(const shortx8*)(whh + (size_t)(m0 + mA0) * HDIM + k + kg0 * 8);
            rah1 = *(const shortx8*)(whh + (size_t)(m0 + mA1) * HDIM + k + kg1 * 8);
            ral0 = *(const shortx8*)(whl + (size_t)(m0 + mA0) * HDIM + k + kg0 * 8);
            ral1 = *(const shortx8*)(whl + (size_t)(m0 + mA1) * HDIM + k + kg1 * 8);
            rbh0 = *(const shortx8*)(wtH + (size_t)(n0 + mA0) * HDIM + k + kg0 * 8);
            rbh1 = *(const shortx8*)(wtH + (size_t)(n0 + mA1) * HDIM + k + kg1 * 8);
            rbl0 = *(const shortx8*)(wtL + (size_t)(n0 + mA0) * HDIM + k + kg0 * 8);
            rbl1 = *(const shortx8*)(wtL + (size_t)(n0 + mA1) * HDIM + k + kg1 * 8);
        }

        shortx8 afh[4], afl[4], bfh[4], bfl[4];
#pragma unroll
        for (int mt = 0; mt < 4; ++mt) {
            afh[mt] = ((const shortx8*)AsH)[quad * 128 + wm + mt * 16 + l15];
            afl[mt] = ((const shortx8*)AsL)[quad * 128 + wm + mt * 16 + l15];
        }
#pragma unroll
        for (int nt = 0; nt < 4; ++nt) {
            bfh[nt] = ((const shortx8*)BsH)[quad * 128 + wn + nt * 16 + l15];
            bfl[nt] = ((const shortx8*)BsL)[quad * 128 + wn + nt * 16 + l15];
        }
#pragma unroll
        for (int mt = 0; mt < 4; ++mt)
#pragma unroll
            for (int nt = 0; nt < 4; ++nt) {
                acc[mt][nt] = __builtin_amdgcn_mfma_f32_16x16x32_bf16(afh[mt], bfh[nt], acc[mt][nt], 0, 0, 0);
                acc[mt][nt] = __builtin_amdgcn_mfma_f32_16x16x32_bf16(afh[mt], bfl[nt], acc[mt][nt], 0, 0, 0);
                acc[mt][nt] = __builtin_amdgcn_mfma_f32_16x16x32_bf16(afl[mt], bfh[nt], acc[mt][nt], 0, 0, 0);
            }
        __syncthreads();
    }

#pragma unroll
    for (int nt = 0; nt < 4; ++nt) {
        int gn = n0 + wn + nt * 16 + l15;
#pragma unroll
        for (int mt = 0; mt < 4; ++mt)
#pragma unroll
            for (int r = 0; r < 4; ++r) {
                int gm = m0 + wm + mt * 16 + quad * 4 + r;
                float a = acc[mt][nt][r];
                __hip_bfloat16 h = __float2bfloat16(a);
                w2h[(size_t)gm * HDIM + gn] = h;
                w2l[(size_t)gm * HDIM + gn] = __float2bfloat16(a - __bfloat162float(h));
            }
    }
}

// ---------------- v = u + Wh*u_shift (hi/lo Wh on B side; t==0 rows keep u) ----------------
__global__ __launch_bounds__(256) void gemm_v_kernel(
    const __hip_bfloat16* __restrict__ ub,
    const __hip_bfloat16* __restrict__ whb,
    const __hip_bfloat16* __restrict__ whl,
    float* __restrict__ out)
{
    __shared__ __align__(16) __hip_bfloat16 As[4 * 128 * 8];
    __shared__ __align__(16) __hip_bfloat16 BsH[4 * 128 * 8];
    __shared__ __align__(16) __hip_bfloat16 BsL[4 * 128 * 8];

    const int j = threadIdx.x;
    const int m0 = blockIdx.x * 128;
    const int n0 = blockIdx.y * 128;
    const int w = j >> 6, lane = j & 63;
    const int wm = (w >> 1) * 64, wn = (w & 1) * 64;
    const int quad = lane >> 4, l15 = lane & 15;

    const int mA0 = j & 127, kg0 = j >> 7;
    const int mA1 = (j + 256) & 127, kg1 = (j + 256) >> 7;

    int rowA0 = m0 + mA0 - 1; if (rowA0 < 0) rowA0 = 0;
    int rowA1 = m0 + mA1 - 1; if (rowA1 < 0) rowA1 = 0;

    floatx4 acc[4][4] = {};

    shortx8 ra0  = *(const shortx8*)(ub  + (size_t)rowA0 * HDIM + kg0 * 8);
    shortx8 ra1  = *(const shortx8*)(ub  + (size_t)rowA1 * HDIM + kg1 * 8);
    shortx8 rbh0 = *(const shortx8*)(whb + (size_t)(n0 + mA0) * HDIM + kg0 * 8);
    shortx8 rbh1 = *(const shortx8*)(whb + (size_t)(n0 + mA1) * HDIM + kg1 * 8);
    shortx8 rbl0 = *(const shortx8*)(whl + (size_t)(n0 + mA0) * HDIM + kg0 * 8);
    shortx8 rbl1 = *(const shortx8*)(whl + (size_t)(n0 + mA1) * HDIM + kg1 * 8);

    for (int kt = 0; kt < 64; ++kt) {
        ((shortx8*)As)[kg0 * 128 + mA0] = ra0;
        ((shortx8*)As)[kg1 * 128 + mA1] = ra1;
        ((shortx8*)BsH)[kg0 * 128 + mA0] = rbh0;
        ((shortx8*)BsH)[kg1 * 128 + mA1] = rbh1;
        ((shortx8*)BsL)[kg0 * 128 + mA0] = rbl0;
        ((shortx8*)BsL)[kg1 * 128 + mA1] = rbl1;
        __syncthreads();

        if (kt < 63) {
            int k = (kt + 1) * 32;
            ra0  = *(const shortx8*)(ub  + (size_t)rowA0 * HDIM + k + kg0 * 8);
            ra1  = *(const shortx8*)(ub  + (size_t)rowA1 * HDIM + k + kg1 * 8);
            rbh0 = *(const shortx8*)(whb + (size_t)(n0 + mA0) * HDIM + k + kg0 * 8);
            rbh1 = *(const shortx8*)(whb + (size_t)(n0 + mA1) * HDIM + k + kg1 * 8);
            rbl0 = *(const shortx8*)(whl + (size_t)(n0 + mA0) * HDIM + k + kg0 * 8);
            rbl1 = *(const shortx8*)(whl + (size_t)(n0 + mA1) * HDIM + k + kg1 * 8);
        }

        shortx8 af[4], bfh[4], bfl[4];
#pragma unroll
        for (int mt = 0; mt < 4; ++mt)
            af[mt] = ((const shortx8*)As)[quad * 128 + wm + mt * 16 + l15];
#pragma unroll
        for (int nt = 0; nt < 4; ++nt) {
            bfh[nt] = ((const shortx8*)BsH)[quad * 128 + wn + nt * 16 + l15];
            bfl[nt] = ((const shortx8*)BsL)[quad * 128 + wn + nt * 16 + l15];
        }
#pragma unroll
        for (int mt = 0; mt < 4; ++mt)
#pragma unroll
            for (int nt = 0; nt < 4; ++nt) {
                acc[mt][nt] = __builtin_amdgcn_mfma_f32_16x16x32_bf16(af[mt], bfh[nt], acc[mt][nt], 0, 0, 0);
                acc[mt][nt] = __builtin_amdgcn_mfma_f32_16x16x32_bf16(af[mt], bfl[nt], acc[mt][nt], 0, 0, 0);
            }
        __syncthreads();
    }

#pragma unroll
    for (int nt = 0; nt < 4; ++nt) {
        int gn = n0 + wn + nt * 16 + l15;
#pragma unroll
        for (int mt = 0; mt < 4; ++mt)
#pragma unroll
            for (int r = 0; r < 4; ++r) {
                int gm = m0 + wm + mt * 16 + quad * 4 + r;
                float uval = out[(size_t)gm * HDIM + gn];
                float res = ((gm & 511) == 0) ? uval : (acc[mt][nt][r] + uval);
                out[(size_t)gm * HDIM + gn] = res;
            }
    }
}

// ---------------- phase B: two parity chains, bf16 hi/lo ring, SENTINEL protocol ----------------
// o_t = v_t + Wh2 * o_{t-2}. 128 WGs x 512 thr: chain=bid&1, rank=bid>>1.
// Ring: [512 slots][hi plane 32768 shorts | lo plane 32768 shorts], written once
// per slot. Pre-filled with 0xFF (word 0xFFFFFFFF = two bf16 NaNs, unreachable
// for finite data) by hipMemsetAsync before the scan; dispatch-end L2 writeback
// makes the sentinel L3-visible. NO FLAGS: consumers read the B-operand with
// agent-scope relaxed 8B atomic loads (L2-bypassing, coherent vs producer's
// agent stores) and retry while any word is still sentinel -- data arrival IS
// the synchronization. This removes, per step: producer's vmcnt(0) drain before
// flag publish, the flag store flight, and the consumer's poll->data RTT
// serialization (~2 L3 round trips + one barrier). ps is double-buffered so
// only ONE __syncthreads per step remains (LDS reduce ordering).
__global__ __launch_bounds__(512, 2) void rnn_scan_kernel(
    const __hip_bfloat16* __restrict__ w2h,
    const __hip_bfloat16* __restrict__ w2l,
    short* __restrict__ ring,                // [512][65536] shorts, sentinel-prefilled
    float* __restrict__ out)
{
    __shared__ float ps[2][8 * 2 * 16 * 17];

    const int j = threadIdx.x;
    const int w = j >> 6, lane = j & 63;
    const int quad = lane >> 4, l15 = lane & 15;
    const int chain = blockIdx.x & 1;
    const int rank = blockIdx.x >> 1;
    const int n0 = rank * 32;

    shortx8 afh[2][8], afl[2][8];
#pragma unroll
    for (int gt = 0; gt < 2; ++gt)
#pragma unroll
        for (int c = 0; c < 8; ++c) {
            int row = n0 + gt * 16 + l15;
            int k = w * 256 + c * 32 + quad * 8;
            afh[gt][c] = *(const shortx8*)(w2h + (size_t)row * HDIM + k);
            afl[gt][c] = *(const shortx8*)(w2l + (size_t)row * HDIM + k);
        }

    const int rn = j & 31, rb = j >> 5;
    const int gt_r = rn >> 4, row_r = rn & 15;

    for (int s = 0; s < 256; ++s) {
        const int t = chain + 2 * s;
        short* slot_next = ring + (size_t)(s * 2 + chain) * 65536;

        // prefetch v (overlaps the data-poll latency)
        float uv = out[(size_t)rb * TH + (size_t)t * HDIM + n0 + rn];

        floatx4 acc[2][2] = {};
        if (s > 0) {
            const short* slot_prev = ring + (size_t)((s - 1) * 2 + chain) * 65536;

            ull vh0[8], vh1[8], vl0[8], vl1[8];
#pragma unroll
            for (int c = 0; c < 8; ++c) {
                const short* p = slot_prev + (w * 32 + c * 4 + quad) * 128 + l15 * 8;
                vh0[c] = __hip_atomic_load((const ull*)p,           __ATOMIC_RELAXED, __HIP_MEMORY_SCOPE_AGENT);
                vh1[c] = __hip_atomic_load((const ull*)(p + 4),     __ATOMIC_RELAXED, __HIP_MEMORY_SCOPE_AGENT);
                vl0[c] = __hip_atomic_load((const ull*)(p + 32768), __ATOMIC_RELAXED, __HIP_MEMORY_SCOPE_AGENT);
                vl1[c] = __hip_atomic_load((const ull*)(p + 32772), __ATOMIC_RELAXED, __HIP_MEMORY_SCOPE_AGENT);
            }
            // retry while any word still sentinel (values are write-once, so
            // re-reading already-valid words is harmless and returns the same bits)
            for (;;) {
                unsigned bad = 0;
#pragma unroll
                for (int c = 0; c < 8; ++c) {
                    bad |= (unsigned)((unsigned)vh0[c] == 0xFFFFFFFFu) | (unsigned)((unsigned)(vh0[c] >> 32) == 0xFFFFFFFFu);
                    bad |= (unsigned)((unsigned)vh1[c] == 0xFFFFFFFFu) | (unsigned)((unsigned)(vh1[c] >> 32) == 0xFFFFFFFFu);
                    bad |= (unsigned)((unsigned)vl0[c] == 0xFFFFFFFFu) | (unsigned)((unsigned)(vl0[c] >> 32) == 0xFFFFFFFFu);
                    bad |= (unsigned)((unsigned)vl1[c] == 0xFFFFFFFFu) | (unsigned)((unsigned)(vl1[c] >> 32) == 0xFFFFFFFFu);
                }
                if (!bad) break;
#pragma unroll
                for (int c = 0; c < 8; ++c) {
                    const short* p = slot_prev + (w * 32 + c * 4 + quad) * 128 + l15 * 8;
                    vh0[c] = __hip_atomic_load((const ull*)p,           __ATOMIC_RELAXED, __HIP_MEMORY_SCOPE_AGENT);
                    vh1[c] = __hip_atomic_load((const ull*)(p + 4),     __ATOMIC_RELAXED, __HIP_MEMORY_SCOPE_AGENT);
                    vl0[c] = __hip_atomic_load((const ull*)(p + 32768), __ATOMIC_RELAXED, __HIP_MEMORY_SCOPE_AGENT);
                    vl1[c] = __hip_atomic_load((const ull*)(p + 32772), __ATOMIC_RELAXED, __HIP_MEMORY_SCOPE_AGENT);
                }
            }

#pragma unroll
            for (int c = 0; c < 8; ++c) {
                union { ull q[2]; shortx8 v; } ubh, ubl;
                ubh.q[0] = vh0[c]; ubh.q[1] = vh1[c];
                ubl.q[0] = vl0[c]; ubl.q[1] = vl1[c];
                shortx8 bh = ubh.v, bl = ubl.v;
                int cp = c & 1;
                acc[0][cp] = __builtin_amdgcn_mfma_f32_16x16x32_bf16(afh[0][c], bh, acc[0][cp], 0, 0, 0);
                acc[0][cp] = __builtin_amdgcn_mfma_f32_16x16x32_bf16(afh[0][c], bl, acc[0][cp], 0, 0, 0);
                acc[0][cp] = __builtin_amdgcn_mfma_f32_16x16x32_bf16(afl[0][c], bh, acc[0][cp], 0, 0, 0);
                acc[1][cp] = __builtin_amdgcn_mfma_f32_16x16x32_bf16(afh[1][c], bh, acc[1][cp], 0, 0, 0);
                acc[1][cp] = __builtin_amdgcn_mfma_f32_16x16x32_bf16(afh[1][c], bl, acc[1][cp], 0, 0, 0);
                acc[1][cp] = __builtin_amdgcn_mfma_f32_16x16x32_bf16(afl[1][c], bh, acc[1][cp], 0, 0, 0);
            }
        }

        floatx4 a0 = acc[0][0] + acc[0][1];
        floatx4 a1 = acc[1][0] + acc[1][1];
        float* psb = ps[s & 1];
#pragma unroll
        for (int r = 0; r < 4; ++r) {
            psb[((w * 2 + 0) * 16 + quad * 4 + r) * 17 + l15] = a0[r];
            psb[((w * 2 + 1) * 16 + quad * 4 + r) * 17 + l15] = a1[r];
        }
        __syncthreads();

        float sv_f = uv;
#pragma unroll
        for (int ww = 0; ww < 8; ++ww)
            sv_f += psb[((ww * 2 + gt_r) * 16 + row_r) * 17 + rb];

        int n = n0 + rn;

        // producer-side hi/lo split, pack (n, n+1) pairs into one 4B relaxed
        // agent store per plane; data arrival at L3 IS the publication.
        __hip_bfloat16 hh = __float2bfloat16(sv_f);
        __hip_bfloat16 ll = __float2bfloat16(sv_f - __bfloat162float(hh));
        unsigned hb = (unsigned)*(unsigned short*)&hh;
        unsigned lb = (unsigned)*(unsigned short*)&ll;
        unsigned hb2 = __shfl_down(hb, 1);
        unsigned lb2 = __shfl_down(lb, 1);
        if ((j & 1) == 0) {
            int idx = (n >> 3) * 128 + rb * 8 + (n & 7);  // n even -> 4B aligned
            __hip_atomic_store((unsigned*)(slot_next + idx), hb | (hb2 << 16),
                               __ATOMIC_RELAXED, __HIP_MEMORY_SCOPE_AGENT);
            __hip_atomic_store((unsigned*)(slot_next + 32768 + idx), lb | (lb2 << 16),
                               __ATOMIC_RELAXED, __HIP_MEMORY_SCOPE_AGENT);
        }

        // out stores: fire-and-forget, off the inter-WG critical path
        out[(size_t)rb * TH + (size_t)t * HDIM + n] = sv_f;
        if (t == TLEN - 1) out[(size_t)OUT_MAIN + (size_t)rb * HDIM + n] = sv_f;
        // no second barrier: ps is double-buffered; the next iteration's
        // barrier orders ps reuse two steps out.
    }
}

// ---------------- launcher ----------------
extern "C" void kernel_launch(void* const* d_in, const int* in_sizes, int n_in,
                              void* d_out, int out_size, void* d_ws, size_t ws_size,
                              hipStream_t stream) {
    (void)in_sizes; (void)n_in; (void)out_size; (void)ws_size;
    const float* x    = (const float*)d_in[0];
    const float* W    = (const float*)d_in[1];
    const float* bias = (const float*)d_in[2];
    float* out = (float*)d_out;
    char* ws = (char*)d_ws;

    // Memory plan (80.0 MB total):
    //  [0,64M): ring bf16 hi/lo (scan only). Aliases, all dead before scan:
    //     xb [0,32M) (dead after gemm_u); whT_hi [0,8M)+whT_lo [8,16M)+whb_lo [16,24M)
    //     (transpose -> gemm_v/gemm_w2); wxb [32,40M) (dead after gemm_u);
    //     whb [40,48M) (dead after gemm_w2); ub [48,80M) lower half (dead after gemm_v).
    //  [64,72M): wh2_hi, [72,80M): wh2_lo -- written by gemm_w2 AFTER gemm_v (ub dead).
    //  Ring sentinel prefill (0xFF bytes) runs AFTER gemm_w2 (all aliases dead);
    //  dispatch-end L2 writeback publishes the sentinel to L3 before the scan.
    __hip_bfloat16* xb     = (__hip_bfloat16*)(ws);
    __hip_bfloat16* whT_hi = (__hip_bfloat16*)(ws);
    __hip_bfloat16* whT_lo = (__hip_bfloat16*)(ws + 8388608);
    __hip_bfloat16* whb_lo = (__hip_bfloat16*)(ws + 16777216);
    short*          ring   = (short*)(ws);
    __hip_bfloat16* wxb    = (__hip_bfloat16*)(ws + 33554432);
    __hip_bfloat16* whb    = (__hip_bfloat16*)(ws + 41943040);
    __hip_bfloat16* ub     = (__hip_bfloat16*)(ws + 50331648);
    __hip_bfloat16* wh2_hi = (__hip_bfloat16*)(ws + 67108864);
    __hip_bfloat16* wh2_lo = (__hip_bfloat16*)(ws + 75497472);

    cast_x_kernel<<<8192, 256, 0, stream>>>(x, xb, OUT_MAIN);
    cast_w_kernel<<<8192, 256, 0, stream>>>(W, wxb, whb);
    gemm_u_kernel<<<dim3(64, 16), 256, 0, stream>>>(xb, wxb, bias, out, ub);
    transpose_wh_kernel<<<dim3(64, 64), dim3(32, 8), 0, stream>>>(W, whT_hi, whT_lo, whb_lo);
    gemm_v_kernel<<<dim3(64, 16), 256, 0, stream>>>(ub, whb, whb_lo, out);
    gemm_w2_kernel<<<dim3(16, 16), 256, 0, stream>>>(whb, whb_lo, whT_hi, whT_lo, wh2_hi, wh2_lo);
    hipMemsetAsync(ring, 0xFF, 67108864, stream);
    rnn_scan_kernel<<<128, 512, 0, stream>>>(wh2_hi, wh2_lo, ring, out);
}

// Round 6
// 1007.240 us; speedup vs baseline: 2.0858x; 2.0858x over previous
//
#include <hip/hip_runtime.h>
#include <hip/hip_fp16.h>
#include <stdint.h>

#define HDIM 2048
#define BATCH 16
#define TLEN 512
#define TH   1048576        // TLEN*HDIM
#define OUT_MAIN 16777216   // BATCH*TLEN*HDIM

using floatx4 = __attribute__((ext_vector_type(4))) float;
using shortx8 = __attribute__((ext_vector_type(8))) short;
using halfx8  = __attribute__((ext_vector_type(8))) _Float16;
typedef unsigned long long ull;

static __device__ __forceinline__ unsigned f16bits(float f) {
    _Float16 h = (_Float16)f;
    return (unsigned)*(unsigned short*)&h;
}

// ---------------- cast kernels ----------------
__global__ void cast_x_kernel(const float* __restrict__ x, _Float16* __restrict__ xh, int n) {
    int i = blockIdx.x * blockDim.x + threadIdx.x;
    int stride = gridDim.x * blockDim.x;
    for (; i < n; i += stride) xh[i] = (_Float16)x[i];
}

__global__ void cast_w_kernel(const float* __restrict__ W,
                              _Float16* __restrict__ wxh,
                              _Float16* __restrict__ whh) {
    int i = blockIdx.x * blockDim.x + threadIdx.x;
    int stride = gridDim.x * blockDim.x;
    for (; i < HDIM * HDIM; i += stride) {
        int g = i >> 11, k = i & (HDIM - 1);
        wxh[i] = (_Float16)W[g * (2 * HDIM) + k];
        whh[i] = (_Float16)W[g * (2 * HDIM) + HDIM + k];
    }
}

// Transpose Wh -> whT (fp16). Runs after gemm_u; output aliases dead xh.
__global__ void transpose_wh_kernel(const float* __restrict__ W,
                                    _Float16* __restrict__ whT) {
    __shared__ float tile[32][33];
    int bx = blockIdx.x * 32, by = blockIdx.y * 32;
    int tx = threadIdx.x, ty = threadIdx.y;  // (32,8)
#pragma unroll
    for (int r = 0; r < 32; r += 8)
        tile[ty + r][tx] = W[(size_t)(by + ty + r) * (2 * HDIM) + HDIM + bx + tx];
    __syncthreads();
#pragma unroll
    for (int r = 0; r < 32; r += 8)
        whT[(size_t)(bx + ty + r) * HDIM + by + tx] = (_Float16)tile[tx][ty + r];
}

// ---------------- phase A: u = x @ Wx^T + b -> out (fp32) + uh (fp16) ----------------
__global__ __launch_bounds__(256) void gemm_u_kernel(
    const _Float16* __restrict__ xh,
    const _Float16* __restrict__ wxh,
    const float* __restrict__ bias,
    float* __restrict__ out,
    _Float16* __restrict__ uh)
{
    __shared__ __align__(16) short As[4 * 128 * 8];
    __shared__ __align__(16) short Bs[4 * 128 * 8];

    const int j = threadIdx.x;
    const int m0 = blockIdx.x * 128;
    const int n0 = blockIdx.y * 128;
    const int w = j >> 6, lane = j & 63;
    const int wm = (w >> 1) * 64, wn = (w & 1) * 64;
    const int quad = lane >> 4, l15 = lane & 15;

    const int mA0 = j & 127, kg0 = j >> 7;
    const int mA1 = (j + 256) & 127, kg1 = (j + 256) >> 7;

    floatx4 acc[4][4] = {};

    shortx8 ra0 = *(const shortx8*)(xh  + (size_t)(m0 + mA0) * HDIM + kg0 * 8);
    shortx8 ra1 = *(const shortx8*)(xh  + (size_t)(m0 + mA1) * HDIM + kg1 * 8);
    shortx8 rb0 = *(const shortx8*)(wxh + (size_t)(n0 + mA0) * HDIM + kg0 * 8);
    shortx8 rb1 = *(const shortx8*)(wxh + (size_t)(n0 + mA1) * HDIM + kg1 * 8);

    for (int kt = 0; kt < 64; ++kt) {
        ((shortx8*)As)[kg0 * 128 + mA0] = ra0;
        ((shortx8*)As)[kg1 * 128 + mA1] = ra1;
        ((shortx8*)Bs)[kg0 * 128 + mA0] = rb0;
        ((shortx8*)Bs)[kg1 * 128 + mA1] = rb1;
        __syncthreads();

        if (kt < 63) {
            int k = (kt + 1) * 32;
            ra0 = *(const shortx8*)(xh  + (size_t)(m0 + mA0) * HDIM + k + kg0 * 8);
            ra1 = *(const shortx8*)(xh  + (size_t)(m0 + mA1) * HDIM + k + kg1 * 8);
            rb0 = *(const shortx8*)(wxh + (size_t)(n0 + mA0) * HDIM + k + kg0 * 8);
            rb1 = *(const shortx8*)(wxh + (size_t)(n0 + mA1) * HDIM + k + kg1 * 8);
        }

        halfx8 af[4], bf[4];
#pragma unroll
        for (int mt = 0; mt < 4; ++mt)
            af[mt] = ((const halfx8*)As)[quad * 128 + wm + mt * 16 + l15];
#pragma unroll
        for (int nt = 0; nt < 4; ++nt)
            bf[nt] = ((const halfx8*)Bs)[quad * 128 + wn + nt * 16 + l15];
#pragma unroll
        for (int mt = 0; mt < 4; ++mt)
#pragma unroll
            for (int nt = 0; nt < 4; ++nt)
                acc[mt][nt] = __builtin_amdgcn_mfma_f32_16x16x32_f16(af[mt], bf[nt], acc[mt][nt], 0, 0, 0);
        __syncthreads();
    }

#pragma unroll
    for (int nt = 0; nt < 4; ++nt) {
        int gn = n0 + wn + nt * 16 + l15;
        float bv = bias[gn];
#pragma unroll
        for (int mt = 0; mt < 4; ++mt) {
#pragma unroll
            for (int r = 0; r < 4; ++r) {
                int gm = m0 + wm + mt * 16 + quad * 4 + r;
                float v = acc[mt][nt][r] + bv;
                out[(size_t)gm * HDIM + gn] = v;
                uh[(size_t)gm * HDIM + gn] = (_Float16)v;
            }
        }
    }
}

// ---------------- Wh2 = Wh*Wh (fp16 single-plane) ----------------
__global__ __launch_bounds__(256) void gemm_w2_kernel(
    const _Float16* __restrict__ whh,
    const _Float16* __restrict__ wT,
    _Float16* __restrict__ w2)
{
    __shared__ __align__(16) short As[4 * 128 * 8];
    __shared__ __align__(16) short Bs[4 * 128 * 8];

    const int j = threadIdx.x;
    const int m0 = blockIdx.x * 128;
    const int n0 = blockIdx.y * 128;
    const int w = j >> 6, lane = j & 63;
    const int wm = (w >> 1) * 64, wn = (w & 1) * 64;
    const int quad = lane >> 4, l15 = lane & 15;

    const int mA0 = j & 127, kg0 = j >> 7;
    const int mA1 = (j + 256) & 127, kg1 = (j + 256) >> 7;

    floatx4 acc[4][4] = {};

    shortx8 ra0 = *(const shortx8*)(whh + (size_t)(m0 + mA0) * HDIM + kg0 * 8);
    shortx8 ra1 = *(const shortx8*)(whh + (size_t)(m0 + mA1) * HDIM + kg1 * 8);
    shortx8 rb0 = *(const shortx8*)(wT  + (size_t)(n0 + mA0) * HDIM + kg0 * 8);
    shortx8 rb1 = *(const shortx8*)(wT  + (size_t)(n0 + mA1) * HDIM + kg1 * 8);

    for (int kt = 0; kt < 64; ++kt) {
        ((shortx8*)As)[kg0 * 128 + mA0] = ra0;
        ((shortx8*)As)[kg1 * 128 + mA1] = ra1;
        ((shortx8*)Bs)[kg0 * 128 + mA0] = rb0;
        ((shortx8*)Bs)[kg1 * 128 + mA1] = rb1;
        __syncthreads();

        if (kt < 63) {
            int k = (kt + 1) * 32;
            ra0 = *(const shortx8*)(whh + (size_t)(m0 + mA0) * HDIM + k + kg0 * 8);
            ra1 = *(const shortx8*)(whh + (size_t)(m0 + mA1) * HDIM + k + kg1 * 8);
            rb0 = *(const shortx8*)(wT  + (size_t)(n0 + mA0) * HDIM + k + kg0 * 8);
            rb1 = *(const shortx8*)(wT  + (size_t)(n0 + mA1) * HDIM + k + kg1 * 8);
        }

        halfx8 af[4], bf[4];
#pragma unroll
        for (int mt = 0; mt < 4; ++mt)
            af[mt] = ((const halfx8*)As)[quad * 128 + wm + mt * 16 + l15];
#pragma unroll
        for (int nt = 0; nt < 4; ++nt)
            bf[nt] = ((const halfx8*)Bs)[quad * 128 + wn + nt * 16 + l15];
#pragma unroll
        for (int mt = 0; mt < 4; ++mt)
#pragma unroll
            for (int nt = 0; nt < 4; ++nt)
                acc[mt][nt] = __builtin_amdgcn_mfma_f32_16x16x32_f16(af[mt], bf[nt], acc[mt][nt], 0, 0, 0);
        __syncthreads();
    }

#pragma unroll
    for (int nt = 0; nt < 4; ++nt) {
        int gn = n0 + wn + nt * 16 + l15;
#pragma unroll
        for (int mt = 0; mt < 4; ++mt)
#pragma unroll
            for (int r = 0; r < 4; ++r) {
                int gm = m0 + wm + mt * 16 + quad * 4 + r;
                w2[(size_t)gm * HDIM + gn] = (_Float16)acc[mt][nt][r];
            }
    }
}

// ---------------- v = u + Wh*u_shift (fp16; t==0 rows keep u) ----------------
__global__ __launch_bounds__(256) void gemm_v_kernel(
    const _Float16* __restrict__ uh,
    const _Float16* __restrict__ whh,
    float* __restrict__ out)
{
    __shared__ __align__(16) short As[4 * 128 * 8];
    __shared__ __align__(16) short Bs[4 * 128 * 8];

    const int j = threadIdx.x;
    const int m0 = blockIdx.x * 128;
    const int n0 = blockIdx.y * 128;
    const int w = j >> 6, lane = j & 63;
    const int wm = (w >> 1) * 64, wn = (w & 1) * 64;
    const int quad = lane >> 4, l15 = lane & 15;

    const int mA0 = j & 127, kg0 = j >> 7;
    const int mA1 = (j + 256) & 127, kg1 = (j + 256) >> 7;

    int rowA0 = m0 + mA0 - 1; if (rowA0 < 0) rowA0 = 0;
    int rowA1 = m0 + mA1 - 1; if (rowA1 < 0) rowA1 = 0;

    floatx4 acc[4][4] = {};

    shortx8 ra0 = *(const shortx8*)(uh  + (size_t)rowA0 * HDIM + kg0 * 8);
    shortx8 ra1 = *(const shortx8*)(uh  + (size_t)rowA1 * HDIM + kg1 * 8);
    shortx8 rb0 = *(const shortx8*)(whh + (size_t)(n0 + mA0) * HDIM + kg0 * 8);
    shortx8 rb1 = *(const shortx8*)(whh + (size_t)(n0 + mA1) * HDIM + kg1 * 8);

    for (int kt = 0; kt < 64; ++kt) {
        ((shortx8*)As)[kg0 * 128 + mA0] = ra0;
        ((shortx8*)As)[kg1 * 128 + mA1] = ra1;
        ((shortx8*)Bs)[kg0 * 128 + mA0] = rb0;
        ((shortx8*)Bs)[kg1 * 128 + mA1] = rb1;
        __syncthreads();

        if (kt < 63) {
            int k = (kt + 1) * 32;
            ra0 = *(const shortx8*)(uh  + (size_t)rowA0 * HDIM + k + kg0 * 8);
            ra1 = *(const shortx8*)(uh  + (size_t)rowA1 * HDIM + k + kg1 * 8);
            rb0 = *(const shortx8*)(whh + (size_t)(n0 + mA0) * HDIM + k + kg0 * 8);
            rb1 = *(const shortx8*)(whh + (size_t)(n0 + mA1) * HDIM + k + kg1 * 8);
        }

        halfx8 af[4], bf[4];
#pragma unroll
        for (int mt = 0; mt < 4; ++mt)
            af[mt] = ((const halfx8*)As)[quad * 128 + wm + mt * 16 + l15];
#pragma unroll
        for (int nt = 0; nt < 4; ++nt)
            bf[nt] = ((const halfx8*)Bs)[quad * 128 + wn + nt * 16 + l15];
#pragma unroll
        for (int mt = 0; mt < 4; ++mt)
#pragma unroll
            for (int nt = 0; nt < 4; ++nt)
                acc[mt][nt] = __builtin_amdgcn_mfma_f32_16x16x32_f16(af[mt], bf[nt], acc[mt][nt], 0, 0, 0);
        __syncthreads();
    }

#pragma unroll
    for (int nt = 0; nt < 4; ++nt) {
        int gn = n0 + wn + nt * 16 + l15;
#pragma unroll
        for (int mt = 0; mt < 4; ++mt)
#pragma unroll
            for (int r = 0; r < 4; ++r) {
                int gm = m0 + wm + mt * 16 + quad * 4 + r;
                float uval = out[(size_t)gm * HDIM + gn];
                float res = ((gm & 511) == 0) ? uval : (acc[mt][nt][r] + uval);
                out[(size_t)gm * HDIM + gn] = res;
            }
    }
}

// ---------------- phase B: two parity chains, fp16 single-plane ring ----------------
// o_t = v_t + Wh2 * o_{t-2}. 128 WGs x 512 thr: chain=bid&1, rank=bid>>1.
// Round-1 flag protocol (proven): write-once slot per step, plain wide loads,
// per-WG flag after vmcnt-draining barrier. fp16 single plane HALVES the ring
// bytes (64KB/WG/step) -- the scan is L3 transaction-throughput bound (round-2
// evidence: 2x transactions -> 2x time), so bytes are the lever. fp16 rel err
// ~5e-4 beats bf16-single 8x; per-step error ~7.5e-4, recursion x1.33 -> ~1e-3.
__global__ __launch_bounds__(512) void rnn_scan_kernel(
    const _Float16* __restrict__ w2,
    short* __restrict__ ring,                // [512][32768] shorts (fp16 bits)
    float* __restrict__ out,
    unsigned* __restrict__ flags)            // [2][64][32] uint, 128B stride
{
    __shared__ float ps[8 * 2 * 16 * 17];

    const int j = threadIdx.x;
    const int w = j >> 6, lane = j & 63;
    const int quad = lane >> 4, l15 = lane & 15;
    const int chain = blockIdx.x & 1;
    const int rank = blockIdx.x >> 1;
    const int n0 = rank * 32;

    unsigned* myflag = flags + (chain * 64 + rank) * 32;
    const unsigned* pollbase = flags + chain * 64 * 32;

    halfx8 af[2][8];
#pragma unroll
    for (int gt = 0; gt < 2; ++gt)
#pragma unroll
        for (int c = 0; c < 8; ++c) {
            int row = n0 + gt * 16 + l15;
            int k = w * 256 + c * 32 + quad * 8;
            af[gt][c] = *(const halfx8*)(w2 + (size_t)row * HDIM + k);
        }

    const int rn = j & 31, rb = j >> 5;
    const int gt_r = rn >> 4, row_r = rn & 15;

    for (int s = 0; s < 256; ++s) {
        const int t = chain + 2 * s;
        short* slot_next = ring + (size_t)(s * 2 + chain) * 32768;

        // prefetch v (overlaps poll latency)
        float uv = out[(size_t)rb * TH + (size_t)t * HDIM + n0 + rn];

        floatx4 acc[2][2] = {};
        if (s > 0) {
            const short* slot_prev = ring + (size_t)((s - 1) * 2 + chain) * 32768;
            // wave-local wait on this chain's 8 producers for wave w's K-slice
            if (lane < 8) {
                const unsigned* fp = pollbase + (w * 8 + lane) * 32;
                while (__hip_atomic_load(fp, __ATOMIC_RELAXED, __HIP_MEMORY_SCOPE_AGENT) < (unsigned)s) {}
            }
            __asm__ __volatile__("" ::: "memory");

#pragma unroll
            for (int c = 0; c < 8; ++c) {
                int kg = w * 32 + c * 4 + quad;
                halfx8 bh = *(const halfx8*)(slot_prev + kg * 128 + l15 * 8);
                int cp = c & 1;
                acc[0][cp] = __builtin_amdgcn_mfma_f32_16x16x32_f16(af[0][c], bh, acc[0][cp], 0, 0, 0);
                acc[1][cp] = __builtin_amdgcn_mfma_f32_16x16x32_f16(af[1][c], bh, acc[1][cp], 0, 0, 0);
            }
        }

        floatx4 a0 = acc[0][0] + acc[0][1];
        floatx4 a1 = acc[1][0] + acc[1][1];
#pragma unroll
        for (int r = 0; r < 4; ++r) {
            ps[((w * 2 + 0) * 16 + quad * 4 + r) * 17 + l15] = a0[r];
            ps[((w * 2 + 1) * 16 + quad * 4 + r) * 17 + l15] = a1[r];
        }
        __syncthreads();

        float sv_f = uv;
#pragma unroll
        for (int ww = 0; ww < 8; ++ww)
            sv_f += ps[((ww * 2 + gt_r) * 16 + row_r) * 17 + rb];

        int n = n0 + rn;

        // fp16 producer-side cast, pack (n, n+1) into one 4B relaxed agent store
        unsigned hb = f16bits(sv_f);
        unsigned hb2 = __shfl_down(hb, 1);
        if ((j & 1) == 0) {
            int idx = (n >> 3) * 128 + rb * 8 + (n & 7);  // n even -> 4B aligned
            __hip_atomic_store((unsigned*)(slot_next + idx), hb | (hb2 << 16),
                               __ATOMIC_RELAXED, __HIP_MEMORY_SCOPE_AGENT);
        }

        // barrier drains ring stores (vmcnt(0) before s_barrier), then publish
        __syncthreads();
        if (j == 0)
            __hip_atomic_store(myflag, (unsigned)(s + 1), __ATOMIC_RELAXED, __HIP_MEMORY_SCOPE_AGENT);

        // out stores AFTER the flag: off the inter-WG critical path
        out[(size_t)rb * TH + (size_t)t * HDIM + n] = sv_f;
        if (t == TLEN - 1) out[(size_t)OUT_MAIN + (size_t)rb * HDIM + n] = sv_f;
    }
}

// ---------------- launcher ----------------
extern "C" void kernel_launch(void* const* d_in, const int* in_sizes, int n_in,
                              void* d_out, int out_size, void* d_ws, size_t ws_size,
                              hipStream_t stream) {
    (void)in_sizes; (void)n_in; (void)out_size; (void)ws_size;
    const float* x    = (const float*)d_in[0];
    const float* W    = (const float*)d_in[1];
    const float* bias = (const float*)d_in[2];
    float* out = (float*)d_out;
    char* ws = (char*)d_ws;

    // Memory plan (80.0 MB + 16KB flags; fp16 single-plane everywhere):
    //  xh   [0,32M)   fp16 x          (dead after gemm_u)
    //  whT  [0,8M)    fp16 Wh^T       (transpose after gemm_u; dead after gemm_w2)
    //  w2   [8,16M)   fp16 Wh^2       (gemm_w2 -> scan)
    //  ring [16,48M)  512 slots x 64KB (scan only; aliases dead xh tail/wxh/whh)
    //  wxh  [32,40M)  fp16 Wx         (dead after gemm_u)
    //  whh  [40,48M)  fp16 Wh         (dead after gemm_w2)
    //  uh   [48,80M)  fp16 u          (dead after gemm_v)
    //  flags [80M,+16K)
    _Float16* xh  = (_Float16*)(ws);
    _Float16* whT = (_Float16*)(ws);
    _Float16* w2  = (_Float16*)(ws + 8388608);
    short*    ring = (short*)(ws + 16777216);
    _Float16* wxh = (_Float16*)(ws + 33554432);
    _Float16* whh = (_Float16*)(ws + 41943040);
    _Float16* uh  = (_Float16*)(ws + 50331648);
    unsigned* flags = (unsigned*)(ws + 83886080);

    hipMemsetAsync(ws + 83886080, 0, 16384, stream);

    cast_x_kernel<<<8192, 256, 0, stream>>>(x, xh, OUT_MAIN);
    cast_w_kernel<<<8192, 256, 0, stream>>>(W, wxh, whh);
    gemm_u_kernel<<<dim3(64, 16), 256, 0, stream>>>(xh, wxh, bias, out, uh);
    transpose_wh_kernel<<<dim3(64, 64), dim3(32, 8), 0, stream>>>(W, whT);
    gemm_v_kernel<<<dim3(64, 16), 256, 0, stream>>>(uh, whh, out);
    gemm_w2_kernel<<<dim3(16, 16), 256, 0, stream>>>(whh, whT, w2);
    rnn_scan_kernel<<<128, 512, 0, stream>>>(w2, ring, out, flags);
}